// Round 6
// baseline (42.997 us; speedup 1.0000x reference)
//
#include <hip/hip_runtime.h>

// GeometricAttention: B=4, N=256, FDIM=256, REL=16, H=8, D=32
//   K[b,i,j] = Kn[b,j] + rel[b,i,j] @ Wk_r          (Kn = nf@Wk_f + bk)
//   scores   = Q.Kn^T + Qr.rel^T                     (Qr = per-head Q @ Wk_r^T)
//   sum_j attn*V = attn@Vn + (attn@rel)@Wv_r         (Vn = nf@Wv_f + bv)
// Round 6: 512-thread blocks everywhere (4 waves/SIMD); wave w owns head w;
// rel transposed in LDS (conflict-free scalar/float2 reads); Wo packed bf16;
// k_qkv split-k (2 halves + LDS reduce); part/wvT aliased into dead rel LDS.

#define BB 4
#define NN 256
#define FD 256
#define RL 16
#define NH 8
#define HD 32

// ws layout (float offsets)
#define OFF_Q    0
#define OFF_KN   (BB*NN*FD)               // ushort KnT[b][f][j]
#define OFF_VN   (OFF_KN + BB*NN*FD/2)    // ushort Vn[b][j][c]
#define OFF_WO   (OFF_VN + BB*NN*FD/2)    // uint WoP[128][256] (bf16 pairs along k)

#define ATP 260   // at[] row stride (floats)
#define RLT 262   // rldsT row stride (floats); 262%32=6 -> 16 r-lanes distinct banks

static __device__ __forceinline__ unsigned short f2bf(float x) {
  unsigned int u = __float_as_uint(x);
  unsigned int r = (u + 0x7fffu + ((u >> 16) & 1u)) >> 16;   // RNE
  return (unsigned short)r;
}
static __device__ __forceinline__ float bf2f(unsigned short h) {
  return __uint_as_float(((unsigned int)h) << 16);
}

// ---------------- Kernel 1: Q(fp32) / KnT(bf16,T) / Vn(bf16) / WoP(bf16 pairs)
__global__ __launch_bounds__(512) void k_qkv6(
    const float* __restrict__ nf,
    const float* __restrict__ Wq, const float* __restrict__ bq,
    const float* __restrict__ Wk, const float* __restrict__ bk,
    const float* __restrict__ Wv, const float* __restrict__ bv,
    const float* __restrict__ Wo,
    float* __restrict__ ws) {
  const int tid = threadIdx.x;
  const int sel = blockIdx.y;          // 0=Q, 1=KnT, 2=Vn, 3=WoP pack
  if (sel == 3) {
    if (tid < 256) {
      const int k2 = blockIdx.x;       // 0..127
      unsigned int lo = f2bf(Wo[(2 * k2) * FD + tid]);
      unsigned int hi = f2bf(Wo[(2 * k2 + 1) * FD + tid]);
      ((unsigned int*)(ws + OFF_WO))[k2 * FD + tid] = lo | (hi << 16);
    }
    return;
  }
  __shared__ __align__(16) float lrowT[FD * 12];   // [k][r] pad-12; reused as red
  const int row0 = blockIdx.x * 8;
  const float* W; const float* bias;
  if (sel == 0)      { W = Wq; bias = bq; }
  else if (sel == 1) { W = Wk; bias = bk; }
  else               { W = Wv; bias = bv; }
  #pragma unroll
  for (int t = 0; t < 4; ++t) {
    int idx = tid + t * 512;           // [0,2048)
    int k = idx & 255, r = idx >> 8;
    lrowT[k * 12 + r] = nf[(row0 + r) * FD + k];
  }
  __syncthreads();
  const int col = tid & 255, half = tid >> 8;
  float acc[8];
  #pragma unroll
  for (int r = 0; r < 8; ++r) acc[r] = 0.f;
  {
    const float* Wp = W + (half * 128) * FD + col;
    const float* lp = lrowT + (half * 128) * 12;
    #pragma unroll 8
    for (int kk = 0; kk < 128; ++kk) {
      const float w = Wp[kk * FD];
      float4 a0 = *(const float4*)&lp[kk * 12];
      float4 a1 = *(const float4*)&lp[kk * 12 + 4];
      acc[0] += a0.x * w; acc[1] += a0.y * w; acc[2] += a0.z * w; acc[3] += a0.w * w;
      acc[4] += a1.x * w; acc[5] += a1.y * w; acc[6] += a1.z * w; acc[7] += a1.w * w;
    }
  }
  __syncthreads();
  float* red = lrowT;                  // [r][col] = 8*256 floats (8KB <= 12KB)
  if (half) {
    #pragma unroll
    for (int r = 0; r < 8; ++r) red[r * 256 + col] = acc[r];
  }
  __syncthreads();
  if (!half) {
    #pragma unroll
    for (int r = 0; r < 8; ++r) acc[r] += red[r * 256 + col];
    const float bb = bias[col];
    if (sel == 1) {
      const int b2 = row0 >> 8, i0 = row0 & 255;
      unsigned short* kout = (unsigned short*)(ws + OFF_KN) + ((size_t)b2 * FD + col) * NN + i0;
      ushort4 v0, v1;
      v0.x = f2bf(acc[0] + bb); v0.y = f2bf(acc[1] + bb);
      v0.z = f2bf(acc[2] + bb); v0.w = f2bf(acc[3] + bb);
      v1.x = f2bf(acc[4] + bb); v1.y = f2bf(acc[5] + bb);
      v1.z = f2bf(acc[6] + bb); v1.w = f2bf(acc[7] + bb);
      ((ushort4*)kout)[0] = v0;
      ((ushort4*)kout)[1] = v1;
    } else if (sel == 2) {
      unsigned short* outp = (unsigned short*)(ws + OFF_VN);
      #pragma unroll
      for (int r = 0; r < 8; ++r)
        outp[(size_t)(row0 + r) * FD + col] = f2bf(acc[r] + bb);
    } else {
      float* outp = ws + OFF_Q;
      #pragma unroll
      for (int r = 0; r < 8; ++r)
        outp[(row0 + r) * FD + col] = acc[r] + bb;
    }
  }
}

// ---------------- Kernel 2: qr + scores + softmax + arel + wv + output
// 512 threads; wave w owns head w for both rows; j/c = {2l,2l+1,2l+128,2l+129}.
__global__ __launch_bounds__(512, 1) void k_attn6(
    const float* __restrict__ rel,
    const float* __restrict__ Wk,
    const float* __restrict__ Wv,
    const float* __restrict__ nf,
    const float* __restrict__ bo,
    float* __restrict__ out,
    float* __restrict__ ws) {
  const float* Q = ws + OFF_Q;
  const unsigned short* KnB = (const unsigned short*)(ws + OFF_KN);
  const unsigned short* VnB = (const unsigned short*)(ws + OFF_VN);
  const unsigned int* WoP = (const unsigned int*)(ws + OFF_WO);

  // XCD-chunked swizzle over 512 blocks (bijective)
  const int bid = (blockIdx.x & 7) * 64 + (blockIdx.x >> 3);
  const int b  = bid >> 7;
  const int i0 = (bid & 127) * 2;
  const int tid = threadIdx.x;
  const int l = tid & 63, w = tid >> 6;

  __shared__ float q[2][FD];                       // 2 KB
  __shared__ float qrs[2][NH * RL];                // 1 KB
  __shared__ __align__(16) float rldsT[2 * RL * RLT];  // 32.75 KB; aliased below
  __shared__ float at[2 * NH * ATP];               // 16.25 KB
  __shared__ float ar[2][NH * RL];                 // 1 KB
  float* part = rldsT;                             // [16][256] after phase C
  float* wvT  = rldsT + 16 * 256;                  // [256][2]

  const float scale = 0.17677669529663687f;        // 1/sqrt(32)
  q[tid >> 8][tid & 255] = Q[(b * NN + i0 + (tid >> 8)) * FD + (tid & 255)] * scale;

  // stage rel transposed: wave w -> row ii = w>>2, channel quad q4 = w&3
  {
    const int ii = w >> 2, q4 = w & 3;
    const float4* rp = (const float4*)(rel + ((size_t)(b * NN + i0 + ii)) * (NN * RL));
    #pragma unroll
    for (int m = 0; m < 4; ++m) {
      const int j = l + 64 * m;
      float4 v = rp[j * 4 + q4];
      rldsT[(ii * RL + 4 * q4 + 0) * RLT + j] = v.x;
      rldsT[(ii * RL + 4 * q4 + 1) * RLT + j] = v.y;
      rldsT[(ii * RL + 4 * q4 + 2) * RLT + j] = v.z;
      rldsT[(ii * RL + 4 * q4 + 3) * RLT + j] = v.w;
    }
  }
  __syncthreads();   // q + rldsT visible

  // qr[ii][h][r] = q[ii][h*32..] . Wk_r rows (first 256 threads)
  if (tid < 256) {
    const int ii = tid >> 7, h = (tid >> 4) & 7, r = tid & 15;
    const float* wrow = Wk + (FD + r) * FD + h * HD;
    const float* qq = &q[ii][h * HD];
    float a = 0.f;
    #pragma unroll
    for (int d = 0; d < HD; ++d) a += qq[d] * wrow[d];
    qrs[ii][h * RL + r] = a;
  }

  // ---- phase A: scores for head w, j = {2l,2l+1,2l+128,2l+129}
  float s[2][4] = {{0.f,0.f,0.f,0.f},{0.f,0.f,0.f,0.f}};
  {
    const ushort2* krow = (const ushort2*)(KnB + ((size_t)b * FD + w * HD) * NN);
    const float* q0 = &q[0][w * HD];
    const float* q1 = &q[1][w * HD];
    #pragma unroll 4
    for (int d = 0; d < HD; ++d) {
      ushort2 ua = krow[d * 128 + l];
      ushort2 ub = krow[d * 128 + 64 + l];
      float k0 = bf2f(ua.x), k1 = bf2f(ua.y), k2 = bf2f(ub.x), k3 = bf2f(ub.y);
      float qa = q0[d], qb = q1[d];
      s[0][0] += qa * k0; s[0][1] += qa * k1; s[0][2] += qa * k2; s[0][3] += qa * k3;
      s[1][0] += qb * k0; s[1][1] += qb * k1; s[1][2] += qb * k2; s[1][3] += qb * k3;
    }
  }
  __syncthreads();   // qrs visible

  // ---- rel-term: s += qr[h=w][r] * relT[r][j]  (conflict-free float2 reads)
  #pragma unroll
  for (int ii = 0; ii < 2; ++ii) {
    #pragma unroll
    for (int r = 0; r < RL; ++r) {
      const float qv = qrs[ii][w * RL + r];
      const float* rr = &rldsT[(ii * RL + r) * RLT];
      float2 ra = *(const float2*)&rr[2 * l];
      float2 rb = *(const float2*)&rr[2 * l + 128];
      s[ii][0] += qv * ra.x; s[ii][1] += qv * ra.y;
      s[ii][2] += qv * rb.x; s[ii][3] += qv * rb.y;
    }
  }

  // ---- phase B: within-wave softmax (wave covers all 256 j of head w)
  #pragma unroll
  for (int ii = 0; ii < 2; ++ii) {
    float v = fmaxf(fmaxf(s[ii][0], s[ii][1]), fmaxf(s[ii][2], s[ii][3]));
    #pragma unroll
    for (int off = 32; off; off >>= 1) v = fmaxf(v, __shfl_xor(v, off));
    float p0 = __expf(s[ii][0] - v), p1 = __expf(s[ii][1] - v);
    float p2 = __expf(s[ii][2] - v), p3 = __expf(s[ii][3] - v);
    float sum = p0 + p1 + p2 + p3;
    #pragma unroll
    for (int off = 32; off; off >>= 1) sum += __shfl_xor(sum, off);
    const float rec = 1.f / sum;
    *(float2*)&at[(ii * NH + w) * ATP + 2 * l]       = make_float2(p0 * rec, p1 * rec);
    *(float2*)&at[(ii * NH + w) * ATP + 2 * l + 128] = make_float2(p2 * rec, p3 * rec);
  }

  // ---- phase C: ar[ii][w][r] = sum_j at[w][j] * relT[r][j] (wave-local at)
  #pragma unroll
  for (int ii = 0; ii < 2; ++ii) {
    const int r = l & 15, q4 = l >> 4;
    const float* arow = &at[(ii * NH + w) * ATP];
    const float* rrow = &rldsT[(ii * RL + r) * RLT];
    float a = 0.f;
    #pragma unroll 4
    for (int jj = 0; jj < 64; ++jj) {
      const int j = 4 * jj + q4;       // interleaved -> bank spread
      a += arow[j] * rrow[j];
    }
    a += __shfl_xor(a, 16);
    a += __shfl_xor(a, 32);
    if (l < 16) ar[ii][w * RL + l] = a;
  }
  __syncthreads();   // at (all heads) + ar visible; rldsT now dead

  // ---- phase D: partial wv over j in [32w,32w+32); c = {2l,2l+1,2l+128,2l+129}
  {
    const int h = l >> 4;              // head of c=2l ; c+128 -> head h+4
    const ushort2* vrow = (const ushort2*)(VnB + (size_t)b * NN * FD);
    float a00=0.f,a01=0.f,a02=0.f,a03=0.f, a10=0.f,a11=0.f,a12=0.f,a13=0.f;
    #pragma unroll 4
    for (int jj = 0; jj < 32; ++jj) {
      const int j = 32 * w + jj;
      ushort2 ua = vrow[j * 128 + l];
      ushort2 ub = vrow[j * 128 + 64 + l];
      float v0 = bf2f(ua.x), v1 = bf2f(ua.y), v2 = bf2f(ub.x), v3 = bf2f(ub.y);
      float p0  = at[h * ATP + j];
      float p0b = at[(h + 4) * ATP + j];
      float p1  = at[(NH + h) * ATP + j];
      float p1b = at[(NH + h + 4) * ATP + j];
      a00 += p0 * v0;  a01 += p0 * v1;  a02 += p0b * v2; a03 += p0b * v3;
      a10 += p1 * v0;  a11 += p1 * v1;  a12 += p1b * v2; a13 += p1b * v3;
    }
    *(float2*)&part[(0 * NH + w) * 256 + 2 * l]       = make_float2(a00, a01);
    *(float2*)&part[(0 * NH + w) * 256 + 2 * l + 128] = make_float2(a02, a03);
    *(float2*)&part[(1 * NH + w) * 256 + 2 * l]       = make_float2(a10, a11);
    *(float2*)&part[(1 * NH + w) * 256 + 2 * l + 128] = make_float2(a12, a13);
  }
  __syncthreads();

  // ---- phase E: reduce 8 wave-partials + Wv_r term -> wvT[c][ii]
  {
    const int ii = tid >> 8, c = tid & 255, h2 = c >> 5;
    float sE = 0.f;
    #pragma unroll
    for (int w2 = 0; w2 < 8; ++w2) sE += part[(ii * NH + w2) * 256 + c];
    #pragma unroll
    for (int r = 0; r < RL; ++r)
      sE += ar[ii][h2 * RL + r] * Wv[(FD + r) * FD + c];
    wvT[c * 2 + ii] = sE;
  }
  __syncthreads();

  // ---- phase F: out[i0+ii][c] = nf + wv[ii] @ Wo + bo  (packed bf16 Wo)
  {
    const int ii = tid >> 8, c = tid & 255;
    float acc = 0.f;
    #pragma unroll 8
    for (int k2 = 0; k2 < 128; ++k2) {
      unsigned int u = WoP[k2 * FD + c];
      float w0 = bf2f((unsigned short)(u & 0xffffu));
      float w1 = bf2f((unsigned short)(u >> 16));
      acc += wvT[(2 * k2) * 2 + ii] * w0 + wvT[(2 * k2 + 1) * 2 + ii] * w1;
    }
    const int row = b * NN + i0 + ii;
    out[row * FD + c] = nf[row * FD + c] + acc + bo[c];
  }
}

extern "C" void kernel_launch(void* const* d_in, const int* in_sizes, int n_in,
                              void* d_out, int out_size, void* d_ws, size_t ws_size,
                              hipStream_t stream) {
  const float* nf  = (const float*)d_in[0];
  const float* rel = (const float*)d_in[1];
  const float* Wq  = (const float*)d_in[2];
  const float* bq  = (const float*)d_in[3];
  const float* Wk  = (const float*)d_in[4];
  const float* bk  = (const float*)d_in[5];
  const float* Wv  = (const float*)d_in[6];
  const float* bv  = (const float*)d_in[7];
  const float* Wo  = (const float*)d_in[8];
  const float* bo  = (const float*)d_in[9];
  float* out = (float*)d_out;
  float* ws  = (float*)d_ws;

  k_qkv6 <<<dim3(BB * NN / 8, 4), 512, 0, stream>>>(nf, Wq, bq, Wk, bk, Wv, bv, Wo, ws);
  k_attn6<<<BB * NN / 2, 512, 0, stream>>>(rel, Wk, Wv, nf, bo, out, ws);
}